// Round 4
// baseline (2760.163 us; speedup 1.0000x reference)
//
#include <hip/hip_runtime.h>

// Problem constants (from reference): N=50000 nodes, E=600000 edges, D=128.
#define D 128

// ---------------------------------------------------------------------------
// CSR build phase A: degree histogram, int4-vectorized over both endpoints.
// ---------------------------------------------------------------------------
__global__ __launch_bounds__(256) void degree_kernel(
    const int* __restrict__ ei, int* __restrict__ deg, int twoE) {
  int i = blockIdx.x * blockDim.x + threadIdx.x;
  int base = i * 4;
  if (base + 3 < twoE) {
    int4 v = *reinterpret_cast<const int4*>(ei + base);
    atomicAdd(&deg[v.x], 1); atomicAdd(&deg[v.y], 1);
    atomicAdd(&deg[v.z], 1); atomicAdd(&deg[v.w], 1);
  } else {
    for (int j = base; j < twoE; ++j) atomicAdd(&deg[ei[j]], 1);
  }
}

// ---------------------------------------------------------------------------
// CSR build phase B: 3-phase exclusive scan over deg[0..n).
// ---------------------------------------------------------------------------
__global__ __launch_bounds__(256) void scan_blocksum(
    const int* __restrict__ deg, int* __restrict__ partials, int n) {
  __shared__ int red[256];
  int t = threadIdx.x;
  int base = blockIdx.x * 1024 + t * 4;
  int s = 0;
#pragma unroll
  for (int j = 0; j < 4; ++j) {
    int i = base + j;
    s += (i < n) ? deg[i] : 0;
  }
  red[t] = s;
  __syncthreads();
#pragma unroll
  for (int w = 128; w > 0; w >>= 1) {
    if (t < w) red[t] += red[t + w];
    __syncthreads();
  }
  if (t == 0) partials[blockIdx.x] = red[0];
}

__global__ __launch_bounds__(64) void scan_partials(int* partials, int nb) {
  __shared__ int tmp[64];
  int t = threadIdx.x;
  int v = (t < nb) ? partials[t] : 0;
  tmp[t] = v;
  __syncthreads();
#pragma unroll
  for (int s = 1; s < 64; s <<= 1) {
    int a = (t >= s) ? tmp[t - s] : 0;
    __syncthreads();
    tmp[t] += a;
    __syncthreads();
  }
  if (t < nb) partials[t] = tmp[t] - v;  // exclusive
}

__global__ __launch_bounds__(256) void scan_final(
    const int* __restrict__ deg, const int* __restrict__ partials,
    int* __restrict__ off, int* __restrict__ cursor, int n) {
  __shared__ int red[256];
  int t = threadIdx.x;
  int base = blockIdx.x * 1024 + t * 4;
  int v[4];
#pragma unroll
  for (int j = 0; j < 4; ++j) v[j] = (base + j < n) ? deg[base + j] : 0;
  int tsum = v[0] + v[1] + v[2] + v[3];
  red[t] = tsum;
  __syncthreads();
#pragma unroll
  for (int s = 1; s < 256; s <<= 1) {
    int a = (t >= s) ? red[t - s] : 0;
    __syncthreads();
    red[t] += a;
    __syncthreads();
  }
  int e = red[t] - tsum + partials[blockIdx.x];
#pragma unroll
  for (int j = 0; j < 4; ++j) {
    if (base + j < n) { off[base + j] = e; cursor[base + j] = e; }
    e += v[j];
  }
}

// ---------------------------------------------------------------------------
// CSR build phase C: scatter edge ids into per-node segments.
// ---------------------------------------------------------------------------
__global__ __launch_bounds__(256) void fill_kernel(
    const int* __restrict__ ei, int* __restrict__ cursor,
    int* __restrict__ elist, int E, int twoE) {
  int i = blockIdx.x * blockDim.x + threadIdx.x;
  if (i >= twoE) return;
  int node = ei[i];
  int e = (i < E) ? i : i - E;
  int pos = atomicAdd(&cursor[node], 1);
  elist[pos] = e;
}

// ---------------------------------------------------------------------------
// Gather: aggr[node][j] = sum over incident edges of edge_attr[e][j].
// 2 nodes per 256-thread block; thread owns one column of one node.
// ---------------------------------------------------------------------------
__global__ __launch_bounds__(256) void gather_kernel(
    const float* __restrict__ edge_attr, const int* __restrict__ off,
    const int* __restrict__ deg, const int* __restrict__ elist,
    float* __restrict__ aggr, int N) {
  int node = blockIdx.x * 2 + (threadIdx.x >> 7);
  int j = threadIdx.x & 127;
  if (node >= N) return;
  int s = off[node];
  int d = deg[node];
  float acc = 0.f;
  int k = 0;
  for (; k + 8 <= d; k += 8) {
    int e[8];
#pragma unroll
    for (int u = 0; u < 8; ++u) e[u] = elist[s + k + u];
    float v[8];
#pragma unroll
    for (int u = 0; u < 8; ++u) v[u] = edge_attr[(long long)e[u] * D + j];
#pragma unroll
    for (int u = 0; u < 8; ++u) acc += v[u];
  }
  for (; k < d; ++k) {
    int e = elist[s + k];
    acc += edge_attr[(long long)e * D + j];
  }
  aggr[(long long)node * D + j] = acc;
}

// ---------------------------------------------------------------------------
// Fused 2-layer MLP: out = (relu([x|aggr] @ W1 + b1)) @ W2 + b2.
// 256 threads / 64 nodes per block. W read directly from global (L1/L2
// resident, full 512B row per half-wave). LDS only holds the A/h tile:
// union{As[64][64] 16KB | Hs[64][128] 32KB} = 32KB -> 4-5 blocks/CU.
// __launch_bounds__(256,4) caps VGPR<=128 -> 4 waves/SIMD.
// ---------------------------------------------------------------------------
__global__ __launch_bounds__(256, 4) void fused_mlp(
    const float* __restrict__ x, const float* __restrict__ aggr,
    const float* __restrict__ W1, const float* __restrict__ b1,
    const float* __restrict__ W2, const float* __restrict__ b2,
    float* __restrict__ outp, int N) {
  constexpr int KC = 64;
  __shared__ float AsHs[64 * D];   // 32KB union
  const int t = threadIdx.x;
  const int tx = t & 31;
  const int ty = t >> 5;
  const int row0 = blockIdx.x * 64;
  const int col = tx * 4;

  float acc[8][4];
  {
    float4 b = *reinterpret_cast<const float4*>(b1 + col);
#pragma unroll
    for (int i = 0; i < 8; ++i) {
      acc[i][0] = b.x; acc[i][1] = b.y; acc[i][2] = b.z; acc[i][3] = b.w;
    }
  }

  // ---- Layer 1: A = [x | aggr], K = 256, chunked by KC=64 ----
  for (int kc = 0; kc < 256; kc += KC) {
    // A tile: 64 rows x 64 cols (stride 64). 16 threads per row.
#pragma unroll
    for (int p = 0; p < 4; ++p) {
      int r = p * 16 + (t >> 4);
      int c4 = (t & 15);
      int gk = kc + c4 * 4;
      int gr = row0 + r;
      float4 v = make_float4(0.f, 0.f, 0.f, 0.f);
      if (gr < N) {
        const float* src = (gk < 128) ? (x + (long long)gr * 128 + gk)
                                      : (aggr + (long long)gr * 128 + (gk - 128));
        v = *reinterpret_cast<const float4*>(src);
      }
      *reinterpret_cast<float4*>(&AsHs[r * KC + c4 * 4]) = v;
    }
    __syncthreads();

    const float* Wp = W1 + (long long)kc * D + col;
#pragma unroll
    for (int k4 = 0; k4 < KC / 4; ++k4) {
      float4 wv0 = *reinterpret_cast<const float4*>(Wp + 0 * D);
      float4 wv1 = *reinterpret_cast<const float4*>(Wp + 1 * D);
      float4 wv2 = *reinterpret_cast<const float4*>(Wp + 2 * D);
      float4 wv3 = *reinterpret_cast<const float4*>(Wp + 3 * D);
      Wp += 4 * D;
#pragma unroll
      for (int i = 0; i < 8; ++i) {
        float4 av = *reinterpret_cast<const float4*>(&AsHs[(ty * 8 + i) * KC + k4 * 4]);
        acc[i][0] += av.x * wv0.x + av.y * wv1.x + av.z * wv2.x + av.w * wv3.x;
        acc[i][1] += av.x * wv0.y + av.y * wv1.y + av.z * wv2.y + av.w * wv3.y;
        acc[i][2] += av.x * wv0.z + av.y * wv1.z + av.z * wv2.z + av.w * wv3.z;
        acc[i][3] += av.x * wv0.w + av.y * wv1.w + av.z * wv2.w + av.w * wv3.w;
      }
    }
    __syncthreads();
  }

  // ReLU, stash h-tile in LDS (stride 128, reuses As region).
#pragma unroll
  for (int i = 0; i < 8; ++i) {
    float4 o = make_float4(fmaxf(acc[i][0], 0.f), fmaxf(acc[i][1], 0.f),
                           fmaxf(acc[i][2], 0.f), fmaxf(acc[i][3], 0.f));
    *reinterpret_cast<float4*>(&AsHs[(ty * 8 + i) * D + col]) = o;
  }
  __syncthreads();

  // ---- Layer 2: A = Hs (all 128 cols already resident), K = 128 ----
  {
    float4 b = *reinterpret_cast<const float4*>(b2 + col);
#pragma unroll
    for (int i = 0; i < 8; ++i) {
      acc[i][0] = b.x; acc[i][1] = b.y; acc[i][2] = b.z; acc[i][3] = b.w;
    }
  }
  {
    const float* Wp = W2 + col;
#pragma unroll
    for (int k4 = 0; k4 < 32; ++k4) {
      float4 wv0 = *reinterpret_cast<const float4*>(Wp + 0 * D);
      float4 wv1 = *reinterpret_cast<const float4*>(Wp + 1 * D);
      float4 wv2 = *reinterpret_cast<const float4*>(Wp + 2 * D);
      float4 wv3 = *reinterpret_cast<const float4*>(Wp + 3 * D);
      Wp += 4 * D;
#pragma unroll
      for (int i = 0; i < 8; ++i) {
        float4 av = *reinterpret_cast<const float4*>(&AsHs[(ty * 8 + i) * D + k4 * 4]);
        acc[i][0] += av.x * wv0.x + av.y * wv1.x + av.z * wv2.x + av.w * wv3.x;
        acc[i][1] += av.x * wv0.y + av.y * wv1.y + av.z * wv2.y + av.w * wv3.y;
        acc[i][2] += av.x * wv0.z + av.y * wv1.z + av.z * wv2.z + av.w * wv3.z;
        acc[i][3] += av.x * wv0.w + av.y * wv1.w + av.z * wv2.w + av.w * wv3.w;
      }
    }
  }

#pragma unroll
  for (int i = 0; i < 8; ++i) {
    int gr = row0 + ty * 8 + i;
    if (gr < N) {
      float4 o = make_float4(acc[i][0], acc[i][1], acc[i][2], acc[i][3]);
      reinterpret_cast<float4*>(outp + (long long)gr * D)[tx] = o;
    }
  }
}

extern "C" void kernel_launch(void* const* d_in, const int* in_sizes, int n_in,
                              void* d_out, int out_size, void* d_ws, size_t ws_size,
                              hipStream_t stream) {
  const float* x         = (const float*)d_in[0];
  const int*   ei        = (const int*)d_in[1];   // [2, E] int32
  const float* edge_attr = (const float*)d_in[2];
  const float* W1        = (const float*)d_in[3];
  const float* b1        = (const float*)d_in[4];
  const float* W2        = (const float*)d_in[5];
  const float* b2        = (const float*)d_in[6];
  const int N = in_sizes[0] / D;
  const int E = in_sizes[2] / D;
  const int twoE = 2 * E;

  // Workspace: [aggr: N*D f32][deg N][off N][cursor N][partials 64][elist 2E]
  float* aggr   = (float*)d_ws;
  int* deg      = (int*)(aggr + (size_t)N * D);
  int* off      = deg + N;
  int* cursor   = off + N;
  int* partials = cursor + N;
  int* elist    = partials + 64;

  const int nb = (N + 1023) / 1024;  // scan blocks (49 for N=50000)

  hipMemsetAsync(deg, 0, (size_t)N * sizeof(int), stream);

  degree_kernel<<<(twoE / 4 + 255) / 256, 256, 0, stream>>>(ei, deg, twoE);
  scan_blocksum<<<nb, 256, 0, stream>>>(deg, partials, N);
  scan_partials<<<1, 64, 0, stream>>>(partials, nb);
  scan_final<<<nb, 256, 0, stream>>>(deg, partials, off, cursor, N);
  fill_kernel<<<(twoE + 255) / 256, 256, 0, stream>>>(ei, cursor, elist, E, twoE);
  gather_kernel<<<(N + 1) / 2, 256, 0, stream>>>(edge_attr, off, deg, elist, aggr, N);

  fused_mlp<<<(N + 63) / 64, 256, 0, stream>>>(x, aggr, W1, b1, W2, b2, (float*)d_out, N);
}

// Round 5
// 789.134 us; speedup vs baseline: 3.4977x; 3.4977x over previous
//
#include <hip/hip_runtime.h>

// Problem constants (from reference): N=50000 nodes, E=600000 edges, D=128.
#define D 128

// ---------------------------------------------------------------------------
// CSR build phase A: degree histogram, int4-vectorized over both endpoints.
// ---------------------------------------------------------------------------
__global__ __launch_bounds__(256) void degree_kernel(
    const int* __restrict__ ei, int* __restrict__ deg, int twoE) {
  int i = blockIdx.x * blockDim.x + threadIdx.x;
  int base = i * 4;
  if (base + 3 < twoE) {
    int4 v = *reinterpret_cast<const int4*>(ei + base);
    atomicAdd(&deg[v.x], 1); atomicAdd(&deg[v.y], 1);
    atomicAdd(&deg[v.z], 1); atomicAdd(&deg[v.w], 1);
  } else {
    for (int j = base; j < twoE; ++j) atomicAdd(&deg[ei[j]], 1);
  }
}

// ---------------------------------------------------------------------------
// CSR build phase B: 3-phase exclusive scan over deg[0..n).
// ---------------------------------------------------------------------------
__global__ __launch_bounds__(256) void scan_blocksum(
    const int* __restrict__ deg, int* __restrict__ partials, int n) {
  __shared__ int red[256];
  int t = threadIdx.x;
  int base = blockIdx.x * 1024 + t * 4;
  int s = 0;
#pragma unroll
  for (int j = 0; j < 4; ++j) {
    int i = base + j;
    s += (i < n) ? deg[i] : 0;
  }
  red[t] = s;
  __syncthreads();
#pragma unroll
  for (int w = 128; w > 0; w >>= 1) {
    if (t < w) red[t] += red[t + w];
    __syncthreads();
  }
  if (t == 0) partials[blockIdx.x] = red[0];
}

__global__ __launch_bounds__(64) void scan_partials(int* partials, int nb) {
  __shared__ int tmp[64];
  int t = threadIdx.x;
  int v = (t < nb) ? partials[t] : 0;
  tmp[t] = v;
  __syncthreads();
#pragma unroll
  for (int s = 1; s < 64; s <<= 1) {
    int a = (t >= s) ? tmp[t - s] : 0;
    __syncthreads();
    tmp[t] += a;
    __syncthreads();
  }
  if (t < nb) partials[t] = tmp[t] - v;  // exclusive
}

__global__ __launch_bounds__(256) void scan_final(
    const int* __restrict__ deg, const int* __restrict__ partials,
    int* __restrict__ off, int* __restrict__ cursor, int n) {
  __shared__ int red[256];
  int t = threadIdx.x;
  int base = blockIdx.x * 1024 + t * 4;
  int v[4];
#pragma unroll
  for (int j = 0; j < 4; ++j) v[j] = (base + j < n) ? deg[base + j] : 0;
  int tsum = v[0] + v[1] + v[2] + v[3];
  red[t] = tsum;
  __syncthreads();
#pragma unroll
  for (int s = 1; s < 256; s <<= 1) {
    int a = (t >= s) ? red[t - s] : 0;
    __syncthreads();
    red[t] += a;
    __syncthreads();
  }
  int e = red[t] - tsum + partials[blockIdx.x];
#pragma unroll
  for (int j = 0; j < 4; ++j) {
    if (base + j < n) { off[base + j] = e; cursor[base + j] = e; }
    e += v[j];
  }
}

// ---------------------------------------------------------------------------
// CSR build phase C: scatter edge ids into per-node segments.
// ---------------------------------------------------------------------------
__global__ __launch_bounds__(256) void fill_kernel(
    const int* __restrict__ ei, int* __restrict__ cursor,
    int* __restrict__ elist, int E, int twoE) {
  int i = blockIdx.x * blockDim.x + threadIdx.x;
  if (i >= twoE) return;
  int node = ei[i];
  int e = (i < E) ? i : i - E;
  int pos = atomicAdd(&cursor[node], 1);
  elist[pos] = e;
}

// ---------------------------------------------------------------------------
// Gather: aggr[node][j] = sum over incident edges of edge_attr[e][j].
// 2 nodes per 256-thread block; thread owns one column of one node.
// ---------------------------------------------------------------------------
__global__ __launch_bounds__(256) void gather_kernel(
    const float* __restrict__ edge_attr, const int* __restrict__ off,
    const int* __restrict__ deg, const int* __restrict__ elist,
    float* __restrict__ aggr, int N) {
  int node = blockIdx.x * 2 + (threadIdx.x >> 7);
  int j = threadIdx.x & 127;
  if (node >= N) return;
  int s = off[node];
  int d = deg[node];
  float acc = 0.f;
  int k = 0;
  for (; k + 8 <= d; k += 8) {
    int e[8];
#pragma unroll
    for (int u = 0; u < 8; ++u) e[u] = elist[s + k + u];
    float v[8];
#pragma unroll
    for (int u = 0; u < 8; ++u) v[u] = edge_attr[(long long)e[u] * D + j];
#pragma unroll
    for (int u = 0; u < 8; ++u) acc += v[u];
  }
  for (; k < d; ++k) {
    int e = elist[s + k];
    acc += edge_attr[(long long)e * D + j];
  }
  aggr[(long long)node * D + j] = acc;
}

// ---------------------------------------------------------------------------
// Fused 2-layer MLP: out = (relu([x|aggr] @ W1 + b1)) @ W2 + b2.
// 256 threads, 128x128 block tile, 8x8 per-thread tile.
// A-operand staged in LDS (KC=32 chunks, 16KB, aliasing the 64KB h-tile
// region); W streamed from global (L1/L2-resident, broadcast across
// row-groups). NO VGPR cap (R4 lesson: launch_bounds(,4) => 64 VGPR =>
// scratch spill catastrophe). LDS 64KB -> 2 blocks/CU; VGPR ~160-256 ->
// 2 waves/SIMD. LDS bytes/FMA ~0.5 (A only) => VALU-bound, not LDS-bound.
// ---------------------------------------------------------------------------
__global__ __launch_bounds__(256) void fused_mlp(
    const float* __restrict__ x, const float* __restrict__ aggr,
    const float* __restrict__ W1, const float* __restrict__ b1,
    const float* __restrict__ W2, const float* __restrict__ b2,
    float* __restrict__ outp, int N) {
  __shared__ float Hs[128 * D];          // 64KB; first 16KB doubles as As
  float* As = Hs;                        // As[128][32], stride 32
  const int t = threadIdx.x;
  const int tx = t & 15;                 // col group: cols 8*tx .. 8*tx+7
  const int ty = t >> 4;                 // row group: rows 8*ty .. 8*ty+7
  const int row0 = blockIdx.x * 128;
  const int col0 = tx * 8;

  float acc[8][8];
  {
    float4 ba = *reinterpret_cast<const float4*>(b1 + col0);
    float4 bb = *reinterpret_cast<const float4*>(b1 + col0 + 4);
#pragma unroll
    for (int i = 0; i < 8; ++i) {
      acc[i][0] = ba.x; acc[i][1] = ba.y; acc[i][2] = ba.z; acc[i][3] = ba.w;
      acc[i][4] = bb.x; acc[i][5] = bb.y; acc[i][6] = bb.z; acc[i][7] = bb.w;
    }
  }

  // ---- Layer 1: A = [x | aggr], K = 256, chunks of KC=32 ----
  for (int kc = 0; kc < 256; kc += 32) {
    const float* Asrc = (kc < 128) ? x : aggr;
    const int koff = (kc < 128) ? kc : (kc - 128);
    // Load As: 128 rows x 32 cols. Thread t loads 4 float4s.
#pragma unroll
    for (int p = 0; p < 4; ++p) {
      int r = (t >> 3) + p * 32;
      int slot = t & 7;                  // float4 index within k-window
      int gr = row0 + r;
      float4 v = make_float4(0.f, 0.f, 0.f, 0.f);
      if (gr < N)
        v = *reinterpret_cast<const float4*>(Asrc + (long long)gr * D + koff + slot * 4);
      *reinterpret_cast<float4*>(&As[r * 32 + slot * 4]) = v;
    }
    __syncthreads();

    const float* Wp = W1 + (long long)kc * D;
#pragma unroll
    for (int k4 = 0; k4 < 8; ++k4) {
      float av[8][4];
#pragma unroll
      for (int i = 0; i < 8; ++i)
        *reinterpret_cast<float4*>(av[i]) =
            *reinterpret_cast<const float4*>(&As[(ty * 8 + i) * 32 + k4 * 4]);
      const float* Wr = Wp + k4 * 4 * D + col0;
#pragma unroll
      for (int kk = 0; kk < 4; ++kk) {
        float4 wa = *reinterpret_cast<const float4*>(Wr + kk * D);
        float4 wb = *reinterpret_cast<const float4*>(Wr + kk * D + 4);
#pragma unroll
        for (int i = 0; i < 8; ++i) {
          float a = av[i][kk];
          acc[i][0] += a * wa.x; acc[i][1] += a * wa.y;
          acc[i][2] += a * wa.z; acc[i][3] += a * wa.w;
          acc[i][4] += a * wb.x; acc[i][5] += a * wb.y;
          acc[i][6] += a * wb.z; acc[i][7] += a * wb.w;
        }
      }
    }
    __syncthreads();
  }

  // ReLU + stash h-tile (128x128) in LDS.
#pragma unroll
  for (int i = 0; i < 8; ++i) {
    float4 oa = make_float4(fmaxf(acc[i][0], 0.f), fmaxf(acc[i][1], 0.f),
                            fmaxf(acc[i][2], 0.f), fmaxf(acc[i][3], 0.f));
    float4 ob = make_float4(fmaxf(acc[i][4], 0.f), fmaxf(acc[i][5], 0.f),
                            fmaxf(acc[i][6], 0.f), fmaxf(acc[i][7], 0.f));
    *reinterpret_cast<float4*>(&Hs[(ty * 8 + i) * D + col0]) = oa;
    *reinterpret_cast<float4*>(&Hs[(ty * 8 + i) * D + col0 + 4]) = ob;
  }
  __syncthreads();

  // ---- Layer 2: A = Hs (fully resident), K = 128 ----
  {
    float4 ba = *reinterpret_cast<const float4*>(b2 + col0);
    float4 bb = *reinterpret_cast<const float4*>(b2 + col0 + 4);
#pragma unroll
    for (int i = 0; i < 8; ++i) {
      acc[i][0] = ba.x; acc[i][1] = ba.y; acc[i][2] = ba.z; acc[i][3] = ba.w;
      acc[i][4] = bb.x; acc[i][5] = bb.y; acc[i][6] = bb.z; acc[i][7] = bb.w;
    }
  }
#pragma unroll 4
  for (int k4 = 0; k4 < 32; ++k4) {
    float av[8][4];
#pragma unroll
    for (int i = 0; i < 8; ++i)
      *reinterpret_cast<float4*>(av[i]) =
          *reinterpret_cast<const float4*>(&Hs[(ty * 8 + i) * D + k4 * 4]);
    const float* Wr = W2 + k4 * 4 * D + col0;
#pragma unroll
    for (int kk = 0; kk < 4; ++kk) {
      float4 wa = *reinterpret_cast<const float4*>(Wr + kk * D);
      float4 wb = *reinterpret_cast<const float4*>(Wr + kk * D + 4);
#pragma unroll
      for (int i = 0; i < 8; ++i) {
        float a = av[i][kk];
        acc[i][0] += a * wa.x; acc[i][1] += a * wa.y;
        acc[i][2] += a * wa.z; acc[i][3] += a * wa.w;
        acc[i][4] += a * wb.x; acc[i][5] += a * wb.y;
        acc[i][6] += a * wb.z; acc[i][7] += a * wb.w;
      }
    }
  }

#pragma unroll
  for (int i = 0; i < 8; ++i) {
    int gr = row0 + ty * 8 + i;
    if (gr < N) {
      float4 oa = make_float4(acc[i][0], acc[i][1], acc[i][2], acc[i][3]);
      float4 ob = make_float4(acc[i][4], acc[i][5], acc[i][6], acc[i][7]);
      *reinterpret_cast<float4*>(outp + (long long)gr * D + col0) = oa;
      *reinterpret_cast<float4*>(outp + (long long)gr * D + col0 + 4) = ob;
    }
  }
}

extern "C" void kernel_launch(void* const* d_in, const int* in_sizes, int n_in,
                              void* d_out, int out_size, void* d_ws, size_t ws_size,
                              hipStream_t stream) {
  const float* x         = (const float*)d_in[0];
  const int*   ei        = (const int*)d_in[1];   // [2, E] int32
  const float* edge_attr = (const float*)d_in[2];
  const float* W1        = (const float*)d_in[3];
  const float* b1        = (const float*)d_in[4];
  const float* W2        = (const float*)d_in[5];
  const float* b2        = (const float*)d_in[6];
  const int N = in_sizes[0] / D;
  const int E = in_sizes[2] / D;
  const int twoE = 2 * E;

  // Workspace: [aggr: N*D f32][deg N][off N][cursor N][partials 64][elist 2E]
  float* aggr   = (float*)d_ws;
  int* deg      = (int*)(aggr + (size_t)N * D);
  int* off      = deg + N;
  int* cursor   = off + N;
  int* partials = cursor + N;
  int* elist    = partials + 64;

  const int nb = (N + 1023) / 1024;  // scan blocks (49 for N=50000)

  hipMemsetAsync(deg, 0, (size_t)N * sizeof(int), stream);

  degree_kernel<<<(twoE / 4 + 255) / 256, 256, 0, stream>>>(ei, deg, twoE);
  scan_blocksum<<<nb, 256, 0, stream>>>(deg, partials, N);
  scan_partials<<<1, 64, 0, stream>>>(partials, nb);
  scan_final<<<nb, 256, 0, stream>>>(deg, partials, off, cursor, N);
  fill_kernel<<<(twoE + 255) / 256, 256, 0, stream>>>(ei, cursor, elist, E, twoE);
  gather_kernel<<<(N + 1) / 2, 256, 0, stream>>>(edge_attr, off, deg, elist, aggr, N);

  fused_mlp<<<(N + 127) / 128, 256, 0, stream>>>(x, aggr, W1, b1, W2, b2, (float*)d_out, N);
}